// Round 1
// baseline (677.396 us; speedup 1.0000x reference)
//
#include <hip/hip_runtime.h>
#include <hip/hip_bf16.h>

typedef unsigned short u16;
typedef unsigned int u32;
typedef __bf16 bf16x8_t __attribute__((ext_vector_type(8)));
typedef float f32x4_t __attribute__((ext_vector_type(4)));

#define BK 64

__device__ __forceinline__ float b2f(u16 v) {
  return __uint_as_float(((u32)v) << 16);
}
__device__ __forceinline__ u16 f2b(float f) {
  __hip_bfloat16 h = __float2bfloat16(f);
  return *reinterpret_cast<u16*>(&h);
}
__device__ __forceinline__ float blo(u32 u) { return __uint_as_float(u << 16); }
__device__ __forceinline__ float bhi(u32 u) { return __uint_as_float(u & 0xffff0000u); }

__device__ __forceinline__ void async_lds16(const u16* g, u16* l) {
  __builtin_amdgcn_global_load_lds(
      (__attribute__((address_space(1))) void*)g,
      (__attribute__((address_space(3))) void*)l, 16, 0, 0);
}

__device__ __forceinline__ void expand8(const float* __restrict__ w,
                                        u16* __restrict__ dst, int I,
                                        int kshift, int gid) {
  const int n = gid >> kshift;
  const int kc = (gid & ((1 << kshift) - 1)) * 8;
  const int K = 8 << kshift;
  const float* wp = w + (size_t)((n >> 3) * I + (kc >> 3)) * 8;
  float4 w0 = *(const float4*)wp;
  float4 w1 = *(const float4*)(wp + 4);
  float w8[8] = {w0.x, w0.y, w0.z, w0.w, w1.x, w1.y, w1.z, w1.w};
  u16 t[8];
  const int r = (n - kc) & 7;
#pragma unroll
  for (int j = 0; j < 8; ++j) t[j] = f2b(w8[(r - j) & 7]);
  *(uint4*)(dst + (size_t)n * K + kc) = *(const uint4*)t;
}

// fp32 -> bf16, 8 elements per thread, vectorized.
__device__ __forceinline__ void cvt8(const float* __restrict__ src,
                                     u16* __restrict__ dst, int gid) {
  const float* p = src + (size_t)gid * 8;
  float4 a = *(const float4*)p;
  float4 b = *(const float4*)(p + 4);
  u16 t[8] = {f2b(a.x), f2b(a.y), f2b(a.z), f2b(a.w),
              f2b(b.x), f2b(b.y), f2b(b.z), f2b(b.w)};
  *(uint4*)(dst + (size_t)gid * 8) = *(const uint4*)t;
}

// blocks [0,8192): circulant weight expansion (4 weights x 2048 blocks).
// blocks [8192, 8192+3*cblocks): q/k/v fp32->bf16 conversion.
__global__ __launch_bounds__(256) void expand_all(
    const float* __restrict__ w_q, const float* __restrict__ w_k,
    const float* __restrict__ w_v, const float* __restrict__ w_fc,
    const float* __restrict__ q, const float* __restrict__ k,
    const float* __restrict__ v, u16* __restrict__ Wq, u16* __restrict__ Wk,
    u16* __restrict__ Wv, u16* __restrict__ Wfc, u16* __restrict__ qb,
    u16* __restrict__ kb, u16* __restrict__ vb, int cblocks) {
  const int e = blockIdx.x;
  if (e < 8192) {
    const int plane = e >> 11;
    const int gid = (e & 2047) * 256 + threadIdx.x;
    if (plane == 0) expand8(w_q, Wq, 128, 7, gid);
    else if (plane == 1) expand8(w_k, Wk, 128, 7, gid);
    else if (plane == 2) expand8(w_v, Wv, 128, 7, gid);
    else expand8(w_fc, Wfc, 512, 9, gid);
  } else {
    const int ce = e - 8192;
    const int plane = ce / cblocks;
    const int gid = (ce - plane * cblocks) * 256 + threadIdx.x;
    if (plane == 0) cvt8(q, qb, gid);
    else if (plane == 1) cvt8(k, kb, gid);
    else cvt8(v, vb, gid);
  }
}

// Y[m,n] = sum_k X[m,k]*W[n,k] + bias[n>>3] (+ res); fp32 accum.
// TILE_M=128, TILE_N=TN (128 or 64). A bf16 via async global_load_lds.
// BK=64, XOR-8 k-block swizzle (conflict-free reads), XCD-chunked grid swizzle.
template <int TN, bool HAS_RES, bool OUT_F32>
__device__ __forceinline__ void gemm_core(
    const u16* __restrict__ Xb, const u16* __restrict__ W,
    const float* __restrict__ bias, const float* __restrict__ res,
    void* __restrict__ Yv, int M, int N, int K, int bid) {
  __shared__ __align__(16) u16 As[128 * BK];
  __shared__ __align__(16) u16 Bs[TN * BK];
  const int tid = threadIdx.x;

  const int grid_m = M >> 7, grid_n = N / TN;
  const int nb = grid_m * grid_n;
  int pid = (bid & 7) * (nb >> 3) + (bid >> 3);
  const int nig = 8 * grid_n;
  const int group_id = pid / nig;
  const int first_m = group_id * 8;
  const int gsz = min(8, grid_m - first_m);
  const int mt = first_m + (pid % gsz);
  const int nt = (pid % nig) / gsz;
  const int m0 = mt << 7, n0 = nt * TN;

  const int lane = tid & 63;
  const int wave = tid >> 6;
  const int wm = (wave >> 1) * 64;
  const int wn = (wave & 1) * (TN / 2);
  const int l16 = lane & 15;
  const int quad = lane >> 4;
  constexpr int NJ = TN >> 5;  // acc cols per wave

  f32x4_t acc[4][NJ] = {};

  const int row0 = tid >> 3;                     // 0..31
  const int kgl = ((tid & 7) ^ (row0 & 7)) * 8;  // swizzled k-block

  for (int k0 = 0; k0 < K; k0 += BK) {
    // B staging: async bf16
#pragma unroll
    for (int it = 0; it < TN / 32; ++it)
      async_lds16(W + (size_t)(n0 + row0 + it * 32) * K + (k0 + kgl),
                  &Bs[(tid + it * 256) * 8]);
    // A staging: async bf16
#pragma unroll
    for (int it = 0; it < 4; ++it)
      async_lds16(Xb + (size_t)(m0 + row0 + it * 32) * K + (k0 + kgl),
                  &As[(tid + it * 256) * 8]);
    __syncthreads();
#pragma unroll
    for (int half = 0; half < 2; ++half) {
      bf16x8_t af[4], bfr[NJ];
#pragma unroll
      for (int i = 0; i < 4; ++i)
        af[i] = *(const bf16x8_t*)&As[(wm + i * 16 + l16) * BK +
                                      (((quad + half * 4) ^ (l16 & 7)) * 8)];
#pragma unroll
      for (int j = 0; j < NJ; ++j)
        bfr[j] = *(const bf16x8_t*)&Bs[(wn + j * 16 + l16) * BK +
                                       (((quad + half * 4) ^ (l16 & 7)) * 8)];
#pragma unroll
      for (int i = 0; i < 4; ++i)
#pragma unroll
        for (int j = 0; j < NJ; ++j)
          acc[i][j] =
              __builtin_amdgcn_mfma_f32_16x16x32_bf16(af[i], bfr[j], acc[i][j], 0, 0, 0);
    }
    __syncthreads();
  }

#pragma unroll
  for (int j = 0; j < NJ; ++j) {
    const int col = n0 + wn + j * 16 + l16;
    const float bv = bias[col >> 3];
#pragma unroll
    for (int i = 0; i < 4; ++i) {
#pragma unroll
      for (int r = 0; r < 4; ++r) {
        const int rw = m0 + wm + i * 16 + quad * 4 + r;
        float vv = acc[i][j][r] + bv;
        if (HAS_RES) vv += res[(size_t)rw * N + col];
        if (OUT_F32)
          ((float*)Yv)[(size_t)rw * N + col] = vv;
        else
          ((u16*)Yv)[(size_t)rw * N + col] = f2b(vv);
      }
    }
  }
}

// q/k/v projections, bf16 inputs (pre-converted). blockIdx.y in {0,1,2}.
__global__ __launch_bounds__(256) void gemm_qkv(
    const u16* __restrict__ X0, const u16* __restrict__ X1,
    const u16* __restrict__ X2, const u16* __restrict__ W0,
    const u16* __restrict__ W1, const u16* __restrict__ W2,
    const float* __restrict__ b0, const float* __restrict__ b1,
    const float* __restrict__ b2, u16* __restrict__ Y0, u16* __restrict__ Y1,
    u16* __restrict__ Y2, int M, int N, int K) {
  const int z = blockIdx.y;
  const u16* X = (z == 0) ? X0 : (z == 1) ? X1 : X2;
  const u16* W = (z == 0) ? W0 : (z == 1) ? W1 : W2;
  const float* bb = (z == 0) ? b0 : (z == 1) ? b1 : b2;
  u16* Y = (z == 0) ? Y0 : (z == 1) ? Y1 : Y2;
  gemm_core<128, false, false>(X, W, bb, nullptr, Y, M, N, K, blockIdx.x);
}

// fc: bf16 A (attn output), fp32 residual + fp32 output, TILE_N=128.
__global__ __launch_bounds__(256) void gemm_fc(
    const u16* __restrict__ X, const u16* __restrict__ W,
    const float* __restrict__ bias, const float* __restrict__ res,
    float* __restrict__ Y, int M, int N, int K) {
  gemm_core<128, true, true>(X, W, bias, res, Y, M, N, K, blockIdx.x);
}

// One wave per (b,h) pair, grid-stride `iters` pairs/wave, no barriers
// (wave-private LDS). V read direct from global (lane-coalesced rows).
__global__ __launch_bounds__(256) void attn_kernel(
    const u16* __restrict__ qp, const u16* __restrict__ kp,
    const u16* __restrict__ vp, float* __restrict__ probs,
    u16* __restrict__ o, int iters) {
  __shared__ __align__(16) u16 Qs[4][8 * 72];
  __shared__ __align__(16) u16 Ks[4][8 * 72];
  __shared__ __align__(16) float Ps[4][64];
  const int tid = threadIdx.x;
  const int wave = tid >> 6;
  const int lane = tid & 63;
  const int r = lane >> 3, c = lane & 7;
  const int ls = r * 72 + c * 8;
  const int qg = r;
  const int kg = c;

  auto pairof = [&](int it) { return (it * gridDim.x + blockIdx.x) * 4 + wave; };
  auto gaddr = [&](int it) {
    const int pr = pairof(it);
    return (size_t)(pr >> 3) * 4096 + (size_t)r * 512 + (pr & 7) * 64 + c * 8;
  };

  uint4 qr = *(const uint4*)(qp + gaddr(0));
  uint4 kr = *(const uint4*)(kp + gaddr(0));

  for (int it = 0; it < iters; ++it) {
    *(uint4*)&Qs[wave][ls] = qr;
    *(uint4*)&Ks[wave][ls] = kr;
    const int pair = pairof(it);
    const int b = pair >> 3;
    const int h = pair & 7;
    // V direct: per k2, 64 lanes read 128B contiguous.
    float vcf[8];
#pragma unroll
    for (int k2 = 0; k2 < 8; ++k2)
      vcf[k2] = b2f(vp[(size_t)b * 4096 + (size_t)k2 * 512 + h * 64 + lane]);
    if (it + 1 < iters) {
      qr = *(const uint4*)(qp + gaddr(it + 1));
      kr = *(const uint4*)(kp + gaddr(it + 1));
    }
    float s = 0.f;
#pragma unroll
    for (int d8 = 0; d8 < 8; ++d8) {
      uint4 qa = *(const uint4*)&Qs[wave][qg * 72 + d8 * 8];
      uint4 ka = *(const uint4*)&Ks[wave][kg * 72 + d8 * 8];
      s += blo(qa.x) * blo(ka.x) + bhi(qa.x) * bhi(ka.x);
      s += blo(qa.y) * blo(ka.y) + bhi(qa.y) * bhi(ka.y);
      s += blo(qa.z) * blo(ka.z) + bhi(qa.z) * bhi(ka.z);
      s += blo(qa.w) * blo(ka.w) + bhi(qa.w) * bhi(ka.w);
    }
    s *= 0.125f;  // 1/sqrt(dk)
    float mx = s;
    mx = fmaxf(mx, __shfl_xor(mx, 1));
    mx = fmaxf(mx, __shfl_xor(mx, 2));
    mx = fmaxf(mx, __shfl_xor(mx, 4));
    float e = __expf(s - mx);
    float sum = e;
    sum += __shfl_xor(sum, 1);
    sum += __shfl_xor(sum, 2);
    sum += __shfl_xor(sum, 4);
    const float p = e / sum;
    probs[(size_t)pair * 64 + lane] = p;
    Ps[wave][lane] = p;  // wave-private, lockstep: no barrier
#pragma unroll
    for (int q2 = 0; q2 < 8; ++q2) {
      float4 p0 = *(const float4*)&Ps[wave][q2 * 8];      // broadcast reads
      float4 p1 = *(const float4*)&Ps[wave][q2 * 8 + 4];
      float acc = p0.x * vcf[0] + p0.y * vcf[1] + p0.z * vcf[2] + p0.w * vcf[3] +
                  p1.x * vcf[4] + p1.y * vcf[5] + p1.z * vcf[6] + p1.w * vcf[7];
      o[(size_t)b * 4096 + q2 * 512 + h * 64 + lane] = f2b(acc);
    }
  }
}

extern "C" void kernel_launch(void* const* d_in, const int* in_sizes, int n_in,
                              void* d_out, int out_size, void* d_ws, size_t ws_size,
                              hipStream_t stream) {
  const float* q = (const float*)d_in[0];
  const float* k = (const float*)d_in[1];
  const float* v = (const float*)d_in[2];
  const float* w_q = (const float*)d_in[3];
  const float* b_q = (const float*)d_in[4];
  const float* w_k = (const float*)d_in[5];
  const float* b_k = (const float*)d_in[6];
  const float* w_v = (const float*)d_in[7];
  const float* b_v = (const float*)d_in[8];
  const float* w_fc = (const float*)d_in[9];
  const float* b_fc = (const float*)d_in[10];

  const int B = in_sizes[0] / 1024;  // 8192
  float* out = (float*)d_out;                   // B*1024 fp32
  float* probs = out + (size_t)B * 1024;        // B*512 fp32 (attn)

  u16* Wq = (u16*)d_ws;
  u16* Wk = Wq + (size_t)4096 * 1024;
  u16* Wv = Wk + (size_t)4096 * 1024;
  u16* Wfc = Wv + (size_t)4096 * 1024;  // 1024x4096
  u16* qb = Wfc + (size_t)4096 * 1024;  // B x 1024 bf16 inputs
  u16* kb = qb + (size_t)B * 1024;
  u16* vb = kb + (size_t)B * 1024;
  u16* scratch = vb + (size_t)B * 1024;
  const size_t fixed_bytes =
      ((size_t)4 * 4096 * 1024 + (size_t)3 * B * 1024) * sizeof(u16);

  // per-row scratch: qp,kp,vp,ao (4096 each), bf16
  const size_t per_row = (size_t)(4 * 4096) * sizeof(u16);
  int chunkB = 128;
  for (int c = B; c >= 128; c >>= 1) {
    if (fixed_bytes + (size_t)c * per_row <= ws_size) { chunkB = c; break; }
  }

  u16* qp = scratch;
  u16* kp = qp + (size_t)chunkB * 4096;
  u16* vp = kp + (size_t)chunkB * 4096;
  u16* ao = vp + (size_t)chunkB * 4096;

  // expand circulant weights + convert q/k/v to bf16, once per call
  const int cblocks = B / 2;  // (B*1024/8)/256 blocks per matrix
  expand_all<<<8192 + 3 * cblocks, 256, 0, stream>>>(
      w_q, w_k, w_v, w_fc, q, k, v, Wq, Wk, Wv, Wfc, qb, kb, vb, cblocks);

  for (int cs = 0; cs < B; cs += chunkB) {
    const int nb_p = (chunkB / 128) * (4096 / 128);
    gemm_qkv<<<dim3(nb_p, 3), 256, 0, stream>>>(
        qb + (size_t)cs * 1024, kb + (size_t)cs * 1024, vb + (size_t)cs * 1024,
        Wq, Wk, Wv, b_q, b_k, b_v, qp, kp, vp, chunkB, 4096, 1024);
    const int ablocks = (chunkB >= 1024) ? 2048 : chunkB * 2;
    const int aiters = (chunkB * 8) / (ablocks * 4);
    attn_kernel<<<ablocks, 256, 0, stream>>>(qp, kp, vp,
                                             probs + (size_t)cs * 512, ao, aiters);
    const int nb_fc = (chunkB / 128) * (1024 / 128);
    gemm_fc<<<nb_fc, 256, 0, stream>>>(ao, Wfc, b_fc, q + (size_t)cs * 1024,
                                       out + (size_t)cs * 1024, chunkB, 1024,
                                       4096);
  }
}

// Round 2
// 612.095 us; speedup vs baseline: 1.1067x; 1.1067x over previous
//
#include <hip/hip_runtime.h>
#include <hip/hip_bf16.h>

typedef unsigned short u16;
typedef unsigned int u32;
typedef __bf16 bf16x8_t __attribute__((ext_vector_type(8)));
typedef float f32x4_t __attribute__((ext_vector_type(4)));

#define BK 64

__device__ __forceinline__ float b2f(u16 v) {
  return __uint_as_float(((u32)v) << 16);
}
__device__ __forceinline__ u16 f2b(float f) {
  __hip_bfloat16 h = __float2bfloat16(f);
  return *reinterpret_cast<u16*>(&h);
}
__device__ __forceinline__ float blo(u32 u) { return __uint_as_float(u << 16); }
__device__ __forceinline__ float bhi(u32 u) { return __uint_as_float(u & 0xffff0000u); }

__device__ __forceinline__ void async_lds16(const u16* g, u16* l) {
  __builtin_amdgcn_global_load_lds(
      (__attribute__((address_space(1))) void*)g,
      (__attribute__((address_space(3))) void*)l, 16, 0, 0);
}

__device__ __forceinline__ void expand8(const float* __restrict__ w,
                                        u16* __restrict__ dst, int I,
                                        int kshift, int gid) {
  const int n = gid >> kshift;
  const int kc = (gid & ((1 << kshift) - 1)) * 8;
  const int K = 8 << kshift;
  const float* wp = w + (size_t)((n >> 3) * I + (kc >> 3)) * 8;
  float4 w0 = *(const float4*)wp;
  float4 w1 = *(const float4*)(wp + 4);
  float w8[8] = {w0.x, w0.y, w0.z, w0.w, w1.x, w1.y, w1.z, w1.w};
  u16 t[8];
  const int r = (n - kc) & 7;
#pragma unroll
  for (int j = 0; j < 8; ++j) t[j] = f2b(w8[(r - j) & 7]);
  *(uint4*)(dst + (size_t)n * K + kc) = *(const uint4*)t;
}

// fp32 -> bf16, 8 elements per thread, vectorized.
__device__ __forceinline__ void cvt8(const float* __restrict__ src,
                                     u16* __restrict__ dst, int gid) {
  const float* p = src + (size_t)gid * 8;
  float4 a = *(const float4*)p;
  float4 b = *(const float4*)(p + 4);
  u16 t[8] = {f2b(a.x), f2b(a.y), f2b(a.z), f2b(a.w),
              f2b(b.x), f2b(b.y), f2b(b.z), f2b(b.w)};
  *(uint4*)(dst + (size_t)gid * 8) = *(const uint4*)t;
}

// blocks [0,8192): circulant weight expansion (4 weights x 2048 blocks).
// blocks [8192, 8192+3*cblocks): q/k/v fp32->bf16 conversion.
__global__ __launch_bounds__(256) void expand_all(
    const float* __restrict__ w_q, const float* __restrict__ w_k,
    const float* __restrict__ w_v, const float* __restrict__ w_fc,
    const float* __restrict__ q, const float* __restrict__ k,
    const float* __restrict__ v, u16* __restrict__ Wq, u16* __restrict__ Wk,
    u16* __restrict__ Wv, u16* __restrict__ Wfc, u16* __restrict__ qb,
    u16* __restrict__ kb, u16* __restrict__ vb, int cblocks) {
  const int e = blockIdx.x;
  if (e < 8192) {
    const int plane = e >> 11;
    const int gid = (e & 2047) * 256 + threadIdx.x;
    if (plane == 0) expand8(w_q, Wq, 128, 7, gid);
    else if (plane == 1) expand8(w_k, Wk, 128, 7, gid);
    else if (plane == 2) expand8(w_v, Wv, 128, 7, gid);
    else expand8(w_fc, Wfc, 512, 9, gid);
  } else {
    const int ce = e - 8192;
    const int plane = ce / cblocks;
    const int gid = (ce - plane * cblocks) * 256 + threadIdx.x;
    if (plane == 0) cvt8(q, qb, gid);
    else if (plane == 1) cvt8(k, kb, gid);
    else cvt8(v, vb, gid);
  }
}

// ---------------------------------------------------------------------------
// 256x256-tile QKV GEMM, BK=32, 4-buffer LDS pipeline, counted vmcnt (T3+T4),
// raw s_barrier (1 per K-tile), setprio around MFMA cluster (T5).
// 512 threads = 8 waves (2 M x 4 N), per-wave output 128x64, acc[8][4].
// LDS swizzle: k-block ^= (row>>1)&3  (bank-even ds_read_b128 on 64B rows),
// applied on pre-swizzled global source (both-sides rule, m104/m231).
// ---------------------------------------------------------------------------
__global__ __launch_bounds__(512, 2) void gemm_qkv256(
    const u16* __restrict__ X0, const u16* __restrict__ X1,
    const u16* __restrict__ X2, const u16* __restrict__ W0,
    const u16* __restrict__ W1, const u16* __restrict__ W2,
    const float* __restrict__ b0, const float* __restrict__ b1,
    const float* __restrict__ b2, u16* __restrict__ Y0, u16* __restrict__ Y1,
    u16* __restrict__ Y2, int M, int N, int K) {
  __shared__ __align__(16) u16 lds[4 * 16384];  // 4 bufs x (A 16KB + B 16KB)
  const int z = blockIdx.y;
  const u16* X = (z == 0) ? X0 : (z == 1) ? X1 : X2;
  const u16* W = (z == 0) ? W0 : (z == 1) ? W1 : W2;
  const float* bias = (z == 0) ? b0 : (z == 1) ? b1 : b2;
  u16* Y = (z == 0) ? Y0 : (z == 1) ? Y1 : Y2;

  const int tid = threadIdx.x;
  const int bid = blockIdx.x;
  const int grid_m = M >> 8, grid_n = N >> 8;
  const int nb = grid_m * grid_n;
  int pid = (bid & 7) * (nb >> 3) + (bid >> 3);  // XCD-chunked swizzle
  const int nig = 8 * grid_n;
  const int group_id = pid / nig;
  const int first_m = group_id * 8;
  const int gsz = min(8, grid_m - first_m);
  const int mt = first_m + (pid % gsz);
  const int ntile = (pid % nig) / gsz;
  const int m0 = mt << 8, n0 = ntile << 8;

  const int lane = tid & 63, wave = tid >> 6;
  const int wm = (wave >> 2) * 128;
  const int wn = (wave & 3) * 64;
  const int l16 = lane & 15, quad = lane >> 4;
  const int kbl = quad ^ ((l16 >> 1) & 3);  // swizzled k-block for frag reads

  // staging: thread -> slots {tid, tid+512}; row = slot>>2, kb = slot&3,
  // source k-block = kb ^ ((row>>1)&3) = (tid&3) ^ ((tid>>3)&3) (same both slots)
  const int srow = tid >> 2;
  const int skbg = (tid & 3) ^ ((tid >> 3) & 3);
  const u16* pA = X + (size_t)(m0 + srow) * K + skbg * 8;
  const u16* pB = W + (size_t)(n0 + srow) * K + skbg * 8;
  const size_t rskip = (size_t)128 * K;

  const int aoff = (wm + l16) * 32 + kbl * 8;
  const int boff = 8192 + (wn + l16) * 32 + kbl * 8;

  f32x4_t acc[8][4] = {};
  const int nt = K >> 5;

  auto stage = [&](int t) {
    u16* l = lds + (t & 3) * 16384;
    const u16* a = pA + t * 32;
    const u16* b = pB + t * 32;
    async_lds16(a, l + tid * 8);
    async_lds16(a + rskip, l + tid * 8 + 4096);
    async_lds16(b, l + 8192 + tid * 8);
    async_lds16(b + rskip, l + 8192 + tid * 8 + 4096);
  };

  // prologue: 3 tiles in flight; order pinned so vmcnt counting is exact
  stage(0);
  __builtin_amdgcn_sched_barrier(0);
  stage(1);
  __builtin_amdgcn_sched_barrier(0);
  stage(2);
  asm volatile("s_waitcnt vmcnt(8)" ::: "memory");  // tile 0 landed
  __builtin_amdgcn_s_barrier();
  __builtin_amdgcn_sched_barrier(0);

  for (int t = 0; t < nt; ++t) {
    if (t + 3 < nt) stage(t + 3);
    const u16* la = lds + (t & 3) * 16384 + aoff;
    const u16* lb = lds + (t & 3) * 16384 + boff;
    bf16x8_t a[8], b[4];
#pragma unroll
    for (int mi = 0; mi < 8; ++mi) a[mi] = *(const bf16x8_t*)(la + mi * 512);
#pragma unroll
    for (int ni = 0; ni < 4; ++ni) b[ni] = *(const bf16x8_t*)(lb + ni * 512);
    __builtin_amdgcn_s_setprio(1);
#pragma unroll
    for (int mi = 0; mi < 8; ++mi)
#pragma unroll
      for (int ni = 0; ni < 4; ++ni)
        acc[mi][ni] = __builtin_amdgcn_mfma_f32_16x16x32_bf16(a[mi], b[ni],
                                                              acc[mi][ni], 0, 0, 0);
    __builtin_amdgcn_s_setprio(0);
    if (t + 1 < nt) {
      // need tile t+1 fully landed; outstanding allowed = tiles {t+2,t+3}
      if (t + 3 < nt)      asm volatile("s_waitcnt vmcnt(8)" ::: "memory");
      else if (t + 2 < nt) asm volatile("s_waitcnt vmcnt(4)" ::: "memory");
      else                 asm volatile("s_waitcnt vmcnt(0)" ::: "memory");
      __builtin_amdgcn_s_barrier();
      __builtin_amdgcn_sched_barrier(0);
    }
  }

#pragma unroll
  for (int ni = 0; ni < 4; ++ni) {
    const int col = n0 + wn + ni * 16 + l16;
    const float bv = bias[col >> 3];
#pragma unroll
    for (int mi = 0; mi < 8; ++mi) {
#pragma unroll
      for (int r = 0; r < 4; ++r) {
        const int rw = m0 + wm + mi * 16 + quad * 4 + r;
        Y[(size_t)rw * N + col] = f2b(acc[mi][ni][r] + bv);
      }
    }
  }
}

// ---------------------------------------------------------------------------
// fc GEMM: proven round-0 structure. TILE_M=128, TILE_N=64, BK=64, 256 thr.
// ---------------------------------------------------------------------------
template <int TN, bool HAS_RES, bool OUT_F32>
__device__ __forceinline__ void gemm_core(
    const u16* __restrict__ Xb, const u16* __restrict__ W,
    const float* __restrict__ bias, const float* __restrict__ res,
    void* __restrict__ Yv, int M, int N, int K, int bid) {
  __shared__ __align__(16) u16 As[128 * BK];
  __shared__ __align__(16) u16 Bs[TN * BK];
  const int tid = threadIdx.x;

  const int grid_m = M >> 7, grid_n = N / TN;
  const int nb = grid_m * grid_n;
  int pid = (bid & 7) * (nb >> 3) + (bid >> 3);
  const int nig = 8 * grid_n;
  const int group_id = pid / nig;
  const int first_m = group_id * 8;
  const int gsz = min(8, grid_m - first_m);
  const int mt = first_m + (pid % gsz);
  const int nt = (pid % nig) / gsz;
  const int m0 = mt << 7, n0 = nt * TN;

  const int lane = tid & 63;
  const int wave = tid >> 6;
  const int wm = (wave >> 1) * 64;
  const int wn = (wave & 1) * (TN / 2);
  const int l16 = lane & 15;
  const int quad = lane >> 4;
  constexpr int NJ = TN >> 5;

  f32x4_t acc[4][NJ] = {};

  const int row0 = tid >> 3;
  const int kgl = ((tid & 7) ^ (row0 & 7)) * 8;

  for (int k0 = 0; k0 < K; k0 += BK) {
#pragma unroll
    for (int it = 0; it < TN / 32; ++it)
      async_lds16(W + (size_t)(n0 + row0 + it * 32) * K + (k0 + kgl),
                  &Bs[(tid + it * 256) * 8]);
#pragma unroll
    for (int it = 0; it < 4; ++it)
      async_lds16(Xb + (size_t)(m0 + row0 + it * 32) * K + (k0 + kgl),
                  &As[(tid + it * 256) * 8]);
    __syncthreads();
#pragma unroll
    for (int half = 0; half < 2; ++half) {
      bf16x8_t af[4], bfr[NJ];
#pragma unroll
      for (int i = 0; i < 4; ++i)
        af[i] = *(const bf16x8_t*)&As[(wm + i * 16 + l16) * BK +
                                      (((quad + half * 4) ^ (l16 & 7)) * 8)];
#pragma unroll
      for (int j = 0; j < NJ; ++j)
        bfr[j] = *(const bf16x8_t*)&Bs[(wn + j * 16 + l16) * BK +
                                       (((quad + half * 4) ^ (l16 & 7)) * 8)];
#pragma unroll
      for (int i = 0; i < 4; ++i)
#pragma unroll
        for (int j = 0; j < NJ; ++j)
          acc[i][j] =
              __builtin_amdgcn_mfma_f32_16x16x32_bf16(af[i], bfr[j], acc[i][j], 0, 0, 0);
    }
    __syncthreads();
  }

#pragma unroll
  for (int j = 0; j < NJ; ++j) {
    const int col = n0 + wn + j * 16 + l16;
    const float bv = bias[col >> 3];
#pragma unroll
    for (int i = 0; i < 4; ++i) {
#pragma unroll
      for (int r = 0; r < 4; ++r) {
        const int rw = m0 + wm + i * 16 + quad * 4 + r;
        float vv = acc[i][j][r] + bv;
        if (HAS_RES) vv += res[(size_t)rw * N + col];
        if (OUT_F32)
          ((float*)Yv)[(size_t)rw * N + col] = vv;
        else
          ((u16*)Yv)[(size_t)rw * N + col] = f2b(vv);
      }
    }
  }
}

// fc: bf16 A (attn output), fp32 residual + fp32 output, TILE_N=64.
__global__ __launch_bounds__(256) void gemm_fc(
    const u16* __restrict__ X, const u16* __restrict__ W,
    const float* __restrict__ bias, const float* __restrict__ res,
    float* __restrict__ Y, int M, int N, int K) {
  gemm_core<64, true, true>(X, W, bias, res, Y, M, N, K, blockIdx.x);
}

// One wave per (b,h) pair, grid-stride `iters` pairs/wave, no barriers
// (wave-private LDS). V read direct from global (lane-coalesced rows).
__global__ __launch_bounds__(256) void attn_kernel(
    const u16* __restrict__ qp, const u16* __restrict__ kp,
    const u16* __restrict__ vp, float* __restrict__ probs,
    u16* __restrict__ o, int iters) {
  __shared__ __align__(16) u16 Qs[4][8 * 72];
  __shared__ __align__(16) u16 Ks[4][8 * 72];
  __shared__ __align__(16) float Ps[4][64];
  const int tid = threadIdx.x;
  const int wave = tid >> 6;
  const int lane = tid & 63;
  const int r = lane >> 3, c = lane & 7;
  const int ls = r * 72 + c * 8;
  const int qg = r;
  const int kg = c;

  auto pairof = [&](int it) { return (it * gridDim.x + blockIdx.x) * 4 + wave; };
  auto gaddr = [&](int it) {
    const int pr = pairof(it);
    return (size_t)(pr >> 3) * 4096 + (size_t)r * 512 + (pr & 7) * 64 + c * 8;
  };

  uint4 qr = *(const uint4*)(qp + gaddr(0));
  uint4 kr = *(const uint4*)(kp + gaddr(0));

  for (int it = 0; it < iters; ++it) {
    *(uint4*)&Qs[wave][ls] = qr;
    *(uint4*)&Ks[wave][ls] = kr;
    const int pair = pairof(it);
    const int b = pair >> 3;
    const int h = pair & 7;
    float vcf[8];
#pragma unroll
    for (int k2 = 0; k2 < 8; ++k2)
      vcf[k2] = b2f(vp[(size_t)b * 4096 + (size_t)k2 * 512 + h * 64 + lane]);
    if (it + 1 < iters) {
      qr = *(const uint4*)(qp + gaddr(it + 1));
      kr = *(const uint4*)(kp + gaddr(it + 1));
    }
    float s = 0.f;
#pragma unroll
    for (int d8 = 0; d8 < 8; ++d8) {
      uint4 qa = *(const uint4*)&Qs[wave][qg * 72 + d8 * 8];
      uint4 ka = *(const uint4*)&Ks[wave][kg * 72 + d8 * 8];
      s += blo(qa.x) * blo(ka.x) + bhi(qa.x) * bhi(ka.x);
      s += blo(qa.y) * blo(ka.y) + bhi(qa.y) * bhi(ka.y);
      s += blo(qa.z) * blo(ka.z) + bhi(qa.z) * bhi(ka.z);
      s += blo(qa.w) * blo(ka.w) + bhi(qa.w) * bhi(ka.w);
    }
    s *= 0.125f;  // 1/sqrt(dk)
    float mx = s;
    mx = fmaxf(mx, __shfl_xor(mx, 1));
    mx = fmaxf(mx, __shfl_xor(mx, 2));
    mx = fmaxf(mx, __shfl_xor(mx, 4));
    float e = __expf(s - mx);
    float sum = e;
    sum += __shfl_xor(sum, 1);
    sum += __shfl_xor(sum, 2);
    sum += __shfl_xor(sum, 4);
    const float p = e / sum;
    probs[(size_t)pair * 64 + lane] = p;
    Ps[wave][lane] = p;  // wave-private, lockstep: no barrier
#pragma unroll
    for (int q2 = 0; q2 < 8; ++q2) {
      float4 p0 = *(const float4*)&Ps[wave][q2 * 8];
      float4 p1 = *(const float4*)&Ps[wave][q2 * 8 + 4];
      float acc = p0.x * vcf[0] + p0.y * vcf[1] + p0.z * vcf[2] + p0.w * vcf[3] +
                  p1.x * vcf[4] + p1.y * vcf[5] + p1.z * vcf[6] + p1.w * vcf[7];
      o[(size_t)b * 4096 + q2 * 512 + h * 64 + lane] = f2b(acc);
    }
  }
}

extern "C" void kernel_launch(void* const* d_in, const int* in_sizes, int n_in,
                              void* d_out, int out_size, void* d_ws, size_t ws_size,
                              hipStream_t stream) {
  const float* q = (const float*)d_in[0];
  const float* k = (const float*)d_in[1];
  const float* v = (const float*)d_in[2];
  const float* w_q = (const float*)d_in[3];
  const float* b_q = (const float*)d_in[4];
  const float* w_k = (const float*)d_in[5];
  const float* b_k = (const float*)d_in[6];
  const float* w_v = (const float*)d_in[7];
  const float* b_v = (const float*)d_in[8];
  const float* w_fc = (const float*)d_in[9];
  const float* b_fc = (const float*)d_in[10];

  const int B = in_sizes[0] / 1024;  // 8192
  float* out = (float*)d_out;                   // B*1024 fp32
  float* probs = out + (size_t)B * 1024;        // B*512 fp32 (attn)

  u16* Wq = (u16*)d_ws;
  u16* Wk = Wq + (size_t)4096 * 1024;
  u16* Wv = Wk + (size_t)4096 * 1024;
  u16* Wfc = Wv + (size_t)4096 * 1024;  // 1024x4096
  u16* qb = Wfc + (size_t)4096 * 1024;  // B x 1024 bf16 inputs
  u16* kb = qb + (size_t)B * 1024;
  u16* vb = kb + (size_t)B * 1024;
  u16* scratch = vb + (size_t)B * 1024;
  const size_t fixed_bytes =
      ((size_t)4 * 4096 * 1024 + (size_t)3 * B * 1024) * sizeof(u16);

  // per-row scratch: qp,kp,vp,ao (4096 each), bf16
  const size_t per_row = (size_t)(4 * 4096) * sizeof(u16);
  int chunkB = 256;
  for (int c = B; c >= 256; c >>= 1) {
    if (fixed_bytes + (size_t)c * per_row <= ws_size) { chunkB = c; break; }
  }

  u16* qp = scratch;
  u16* kp = qp + (size_t)chunkB * 4096;
  u16* vp = kp + (size_t)chunkB * 4096;
  u16* ao = vp + (size_t)chunkB * 4096;

  // expand circulant weights + convert q/k/v to bf16, once per call
  const int cblocks = B / 2;
  expand_all<<<8192 + 3 * cblocks, 256, 0, stream>>>(
      w_q, w_k, w_v, w_fc, q, k, v, Wq, Wk, Wv, Wfc, qb, kb, vb, cblocks);

  for (int cs = 0; cs < B; cs += chunkB) {
    const int nb_p = (chunkB / 256) * (4096 / 256);
    gemm_qkv256<<<dim3(nb_p, 3), 512, 0, stream>>>(
        qb + (size_t)cs * 1024, kb + (size_t)cs * 1024, vb + (size_t)cs * 1024,
        Wq, Wk, Wv, b_q, b_k, b_v, qp, kp, vp, chunkB, 4096, 1024);
    const int ablocks = (chunkB >= 1024) ? 2048 : chunkB * 2;
    const int aiters = (chunkB * 8) / (ablocks * 4);
    attn_kernel<<<ablocks, 256, 0, stream>>>(qp, kp, vp,
                                             probs + (size_t)cs * 512, ao, aiters);
    const int nb_fc = (chunkB / 128) * (1024 / 64);
    gemm_fc<<<nb_fc, 256, 0, stream>>>(ao, Wfc, b_fc, q + (size_t)cs * 1024,
                                       out + (size_t)cs * 1024, chunkB, 1024,
                                       4096);
  }
}